// Round 2
// 2480.153 us; speedup vs baseline: 2.3996x; 2.3996x over previous
//
#include <hip/hip_runtime.h>
#include <hip/hip_bf16.h>

#define NEXP  8
#define DM    1024
#define VOCAB 32000
#define BATCH 4096
#define TM    128
#define TN    128
#define BK    32

typedef short bf16x8 __attribute__((ext_vector_type(8)));
typedef float f32x4  __attribute__((ext_vector_type(4)));

// ---------------- routing: counts -> offsets -> permutation ----------------
__global__ void route_kernel(const int* __restrict__ ptr,
                             int* __restrict__ gstart,
                             int* __restrict__ perm)
{
    __shared__ int cnt[NEXP];
    __shared__ int cur[NEXP];
    int tid = threadIdx.x;
    if (tid < NEXP) cnt[tid] = 0;
    __syncthreads();
    for (int r = tid; r < BATCH; r += blockDim.x) {
        int e = ptr[r] & (NEXP - 1);
        atomicAdd(&cnt[e], 1);
    }
    __syncthreads();
    if (tid == 0) {
        int acc = 0;
        for (int e = 0; e < NEXP; ++e) {
            gstart[e] = acc;
            cur[e] = acc;
            acc += cnt[e];
        }
        gstart[NEXP] = acc; // == BATCH
    }
    __syncthreads();
    for (int r = tid; r < BATCH; r += blockDim.x) {
        int e = ptr[r] & (NEXP - 1);
        int pos = atomicAdd(&cur[e], 1);
        perm[pos] = r;
    }
}

// ---------------- gather x rows -> group-contiguous bf16 A ----------------
// grid = BATCH + TM blocks (pad rows zero-filled), 256 threads, 4 elems/thread
__global__ void pack_kernel(const float* __restrict__ x,
                            const int* __restrict__ perm,
                            __hip_bfloat16* __restrict__ Ap)
{
    int p   = blockIdx.x;
    int tid = threadIdx.x;
    __hip_bfloat16* dst = Ap + (size_t)p * DM + tid * 4;
    if (p >= BATCH) {
        *(unsigned long long*)dst = 0ull;
        return;
    }
    int r = perm[p];
    const float4 v = *(const float4*)(x + (size_t)r * DM + tid * 4);
    union { __hip_bfloat162 h[2]; unsigned long long q; } cv;
    cv.h[0] = __float22bfloat162_rn(make_float2(v.x, v.y));
    cv.h[1] = __float22bfloat162_rn(make_float2(v.z, v.w));
    *(unsigned long long*)dst = cv.q;
}

// ---------------- grouped GEMM, persistent (n-tile, expert) blocks ----------
// grid = (VOCAB/TN = 250, NEXP = 8): every block has real work (no empty-block
// storm), and 250 % 8 != 0 spreads n-tiles across all 8 XCDs. Each block loops
// its expert's <= ~5 m-tiles internally. K-loop body and epilogue are the
// round-0 proven versions, unchanged.
__global__ __launch_bounds__(256) void moe_gemm_kernel(
    const __hip_bfloat16* __restrict__ Ap,   // [BATCH+TM][DM] bf16, grouped
    const float* __restrict__ W,             // [E][VOCAB][DM] fp32
    const float* __restrict__ bias,          // [E][VOCAB] fp32
    const int* __restrict__ gstart,          // [E+1]
    const int* __restrict__ perm,            // [BATCH]
    float* __restrict__ out)                 // [BATCH][VOCAB] fp32
{
    const int nt = blockIdx.x;
    const int e  = blockIdx.y;
    const int g0 = gstart[e];
    const int ne = gstart[e + 1] - g0;
    if (ne <= 0) return;
    const int nmt = (ne + TM - 1) / TM;
    const int n0  = nt * TN;

    __shared__ __hip_bfloat16 Asm[TM * BK];  // 8 KB
    __shared__ __hip_bfloat16 Bsm[TN * BK];  // 8 KB

    const int tid  = threadIdx.x;
    const int lane = tid & 63;
    const int wave = tid >> 6;
    const int wm   = (wave & 1) * 64;   // wave's m offset in tile
    const int wn   = (wave >> 1) * 64;  // wave's n offset in tile
    const int l16  = lane & 15;
    const int quad = lane >> 4;

    // A staging geometry: per wave-instr 64 lanes x 16B = 16 rows of [32 bf16]
    const int arow = wave * 16 + (lane >> 2);   // row within 64-row chunk
    const int acol = (lane & 3) * 8;            // bf16 element offset in BK

    const float* Wb = W + ((size_t)e * VOCAB + n0) * DM;

    // bias hoisted: col = n0 + wn + j*16 + l16, invariant across m-tiles
    float bj[4];
    #pragma unroll
    for (int j = 0; j < 4; ++j)
        bj[j] = bias[(size_t)e * VOCAB + n0 + wn + j * 16 + l16];

    for (int mt = 0; mt < nmt; ++mt) {
        const int m0 = mt * TM;
        const __hip_bfloat16* Ab = Ap + (size_t)(g0 + m0) * DM;
        f32x4 acc[4][4] = {};

        for (int k0 = 0; k0 < DM; k0 += BK) {
            __syncthreads();
            // ---- stage A tile (bf16, async direct-to-LDS, 16B/lane) ----
            #pragma unroll
            for (int t = 0; t < 2; ++t) {
                const __hip_bfloat16* src = Ab + (size_t)(t * 64 + arow) * DM + k0 + acol;
                __builtin_amdgcn_global_load_lds(
                    (const __attribute__((address_space(1))) void*)src,
                    (__attribute__((address_space(3))) void*)(Asm + (t * 64 + wave * 16) * BK),
                    16, 0, 0);
            }
            // ---- stage B tile: fp32 W -> bf16 LDS (fused convert) ----
            #pragma unroll
            for (int t = 0; t < 4; ++t) {
                int u   = t * 256 + tid;      // 0..1023
                int row = u >> 3;             // 0..127
                int c4  = (u & 7) * 4;        // fp32 col in BK
                const float4 v = *(const float4*)(Wb + (size_t)row * DM + k0 + c4);
                union { __hip_bfloat162 h[2]; unsigned long long q; } cv;
                cv.h[0] = __float22bfloat162_rn(make_float2(v.x, v.y));
                cv.h[1] = __float22bfloat162_rn(make_float2(v.z, v.w));
                *(unsigned long long*)(Bsm + row * BK + c4) = cv.q;
            }
            __syncthreads();
            // ---- fragments + MFMA 4x4 of 16x16x32 per wave ----
            bf16x8 av[4], bv[4];
            #pragma unroll
            for (int i = 0; i < 4; ++i)
                av[i] = *(const bf16x8*)(Asm + (wm + i * 16 + l16) * BK + quad * 8);
            #pragma unroll
            for (int j = 0; j < 4; ++j)
                bv[j] = *(const bf16x8*)(Bsm + (wn + j * 16 + l16) * BK + quad * 8);
            #pragma unroll
            for (int i = 0; i < 4; ++i) {
                #pragma unroll
                for (int j = 0; j < 4; ++j) {
                    acc[i][j] = __builtin_amdgcn_mfma_f32_16x16x32_bf16(
                        av[i], bv[j], acc[i][j], 0, 0, 0);
                }
            }
        }

        // ---- epilogue (round-0 proven): bias + scatter through perm ----
        // C/D layout: col = lane&15, row = quad*4 + reg
        #pragma unroll
        for (int j = 0; j < 4; ++j) {
            const int col = n0 + wn + j * 16 + l16;
            const float bv_ = bj[j];
            #pragma unroll
            for (int i = 0; i < 4; ++i) {
                #pragma unroll
                for (int r = 0; r < 4; ++r) {
                    int pr = m0 + wm + i * 16 + quad * 4 + r;
                    if (pr < ne) {
                        int orow = perm[g0 + pr];
                        out[(size_t)orow * VOCAB + col] = acc[i][j][r] + bv_;
                    }
                }
            }
        }
        // no barrier needed here: epilogue touches no LDS; next mt's first
        // k-loop __syncthreads() orders epilogue-frag-reads vs restaging
    }
}

extern "C" void kernel_launch(void* const* d_in, const int* in_sizes, int n_in,
                              void* d_out, int out_size, void* d_ws, size_t ws_size,
                              hipStream_t stream)
{
    const float* x   = (const float*)d_in[0];
    const int*   ptr = (const int*)d_in[1];
    const float* W   = (const float*)d_in[2];
    const float* b   = (const float*)d_in[3];
    float* out = (float*)d_out;

    char* ws = (char*)d_ws;
    int* gstart = (int*)ws;                              // 16 ints
    int* perm   = (int*)(ws + 64);                       // 4096 ints
    __hip_bfloat16* Ap = (__hip_bfloat16*)(ws + 32768);  // (4096+128)*1024 bf16

    route_kernel<<<1, 256, 0, stream>>>(ptr, gstart, perm);
    pack_kernel<<<BATCH + TM, 256, 0, stream>>>(x, perm, Ap);
    dim3 grid(VOCAB / TN, NEXP);
    moe_gemm_kernel<<<grid, 256, 0, stream>>>(Ap, W, b, gstart, perm, out);
}